// Round 1
// baseline (178.439 us; speedup 1.0000x reference)
//
#include <hip/hip_runtime.h>
#include <math.h>

#define KNOTS 8
#define HIDN 32
#define TT 4096
#define CC 512
#define NB 32
#define BOUNDF 5.0f
#define PSTRIDE 78   // floats per param row in ws/LDS
#define BINOFF 12    // float offset of bin table within a row

// ---------------- Kernel 1: per-row moments + MLP -> spline params ----------------
__global__ __launch_bounds__(1024, 4)
void k_stats(const float* __restrict__ x, const float* __restrict__ W1,
             const float* __restrict__ b1, const float* __restrict__ W2,
             const float* __restrict__ b2, float* __restrict__ ws)
{
    const int bb = blockIdx.y;          // batch 0..31
    const int c0 = blockIdx.x * 64;     // c-tile base
    const int ci = threadIdx.x & 63;
    const int tg = threadIdx.x >> 6;    // 0..15

    const float* px = x + (size_t)bb * TT * CC + c0 + ci;
    float s1 = 0.f, s2 = 0.f, s3 = 0.f, s4 = 0.f;
    #pragma unroll 4
    for (int t = tg; t < TT; t += 16) {
        float v  = px[(size_t)t * CC];
        float v2 = v * v;
        s1 += v;
        s2 = fmaf(v,  v,  s2);
        s3 = fmaf(v2, v,  s3);
        s4 = fmaf(v2, v2, s4);
    }

    __shared__ float red[16][4][64];
    red[tg][0][ci] = s1; red[tg][1][ci] = s2; red[tg][2][ci] = s3; red[tg][3][ci] = s4;
    __syncthreads();

    __shared__ float mom[4][64];
    if (threadIdx.x < 256) {
        const int m = threadIdx.x >> 6, c = threadIdx.x & 63;
        float acc = 0.f;
        #pragma unroll
        for (int g = 0; g < 16; ++g) acc += red[g][m][c];
        mom[m][c] = acc;
    }
    __syncthreads();
    if (threadIdx.x >= 64) return;

    // ---- per-row finalize: one lane per row ----
    const float n  = (float)TT;
    const float t1 = mom[0][ci], t2 = mom[1][ci], t3 = mom[2][ci], t4 = mom[3][ci];
    const float mu  = t1 / n;
    const float ex2 = t2 / n, ex3 = t3 / n, ex4 = t4 / n;
    float var = (t2 - n * mu * mu) / (n - 1.f);
    var = fmaxf(var, 0.f);
    const float sig  = fmaxf(sqrtf(var), 1e-4f);
    const float inv  = 1.f / sig;
    const float mu2  = mu * mu;
    const float ez3  = ex3 - 3.f * mu * ex2 + 2.f * mu * mu2;
    const float ez4  = ex4 - 4.f * mu * ex3 + 6.f * mu2 * ex2 - 3.f * mu2 * mu2;
    const float inv2 = inv * inv;
    const float skew  = ez3 * inv2 * inv;
    const float ekurt = ez4 * inv2 * inv2 - 3.f;

    // MLP: hid = relu(stats @ W1^T + b1)
    float hid[HIDN];
    #pragma unroll
    for (int h = 0; h < HIDN; ++h) {
        float v = fmaf(W1[2*h], skew, fmaf(W1[2*h+1], ekurt, b1[h]));
        hid[h] = fmaxf(v, 0.f);
    }

    // raw[0..7] -> widths softmax -> kx knots
    float e[KNOTS], kxr[KNOTS+1], kyr[KNOTS+1], dr[KNOTS+1];
    {
        float mx = -1e30f;
        #pragma unroll
        for (int o = 0; o < KNOTS; ++o) {
            float acc = b2[o];
            #pragma unroll
            for (int h = 0; h < HIDN; ++h) acc = fmaf(W2[o*HIDN + h], hid[h], acc);
            e[o] = acc; mx = fmaxf(mx, acc);
        }
        float sum = 0.f;
        #pragma unroll
        for (int o = 0; o < KNOTS; ++o) { e[o] = expf(e[o] - mx); sum += e[o]; }
        const float scale = (2.f * BOUNDF) / sum;
        float cum = -BOUNDF; kxr[0] = -BOUNDF;
        #pragma unroll
        for (int o = 0; o < KNOTS; ++o) { cum = fmaf(e[o], scale, cum); kxr[o+1] = cum; }
    }
    // raw[8..15] -> heights softmax -> ky knots
    {
        float mx = -1e30f;
        #pragma unroll
        for (int o = 0; o < KNOTS; ++o) {
            float acc = b2[KNOTS + o];
            #pragma unroll
            for (int h = 0; h < HIDN; ++h) acc = fmaf(W2[(KNOTS+o)*HIDN + h], hid[h], acc);
            e[o] = acc; mx = fmaxf(mx, acc);
        }
        float sum = 0.f;
        #pragma unroll
        for (int o = 0; o < KNOTS; ++o) { e[o] = expf(e[o] - mx); sum += e[o]; }
        const float scale = (2.f * BOUNDF) / sum;
        float cum = -BOUNDF; kyr[0] = -BOUNDF;
        #pragma unroll
        for (int o = 0; o < KNOTS; ++o) { cum = fmaf(e[o], scale, cum); kyr[o+1] = cum; }
    }
    // raw[16..24] -> derivs = softplus + 1e-3
    #pragma unroll
    for (int o = 0; o < KNOTS+1; ++o) {
        float acc = b2[2*KNOTS + o];
        #pragma unroll
        for (int h = 0; h < HIDN; ++h) acc = fmaf(W2[(2*KNOTS+o)*HIDN + h], hid[h], acc);
        float sp = fmaxf(acc, 0.f) + log1pf(expf(-fabsf(acc)));
        dr[o] = sp + 1e-3f;
    }

    // ---- write param row ----
    float* row = ws + (size_t)(bb * CC + c0 + ci) * PSTRIDE;
    row[0] = inv;            // a
    row[1] = -mu * inv;      // b  (z = fma(x, a, b))
    #pragma unroll
    for (int j = 1; j <= 7; ++j) row[1 + j] = kxr[j];   // kx[1..7] at [2..8]
    #pragma unroll
    for (int j = 0; j < KNOTS; ++j) {
        const float w  = kxr[j+1] - kxr[j];
        const float wm = fmaxf(w, 1e-8f);
        const float h  = kyr[j+1] - kyr[j];
        const float s  = h / wm;
        float* bin = row + BINOFF + j * 8;
        bin[0] = kxr[j];                    // kx_l
        bin[1] = 1.f / wm;                  // 1/w
        bin[2] = kyr[j];                    // ky_l
        bin[3] = h * s;                     // P
        bin[4] = h * dr[j];                 // Q
        bin[5] = dr[j+1] + dr[j] - 2.f*s;   // R
        bin[6] = s;                         // S
    }
}

// ---------------- Kernel 2: apply RQS spline elementwise ----------------
__global__ __launch_bounds__(256, 4)
void k_apply(const float* __restrict__ x, const float* __restrict__ ws,
             float* __restrict__ out)
{
    const int tch   = blockIdx.x;   // 0..7  (t chunk of 512)
    const int ctile = blockIdx.y;   // 0..7
    const int bb    = blockIdx.z;   // 0..31
    const int c0 = ctile * 64;
    const int ci = threadIdx.x & 63;
    const int tg = threadIdx.x >> 6;  // 0..3

    __shared__ float sp[64 * PSTRIDE];
    {
        const float* src = ws + (size_t)(bb * CC + c0) * PSTRIDE;
        for (int i = threadIdx.x; i < 64 * PSTRIDE; i += 256) sp[i] = src[i];
    }
    __syncthreads();

    const int rb = ci * PSTRIDE;
    const float a  = sp[rb + 0];
    const float bz = sp[rb + 1];
    const float kx1 = sp[rb + 2], kx2 = sp[rb + 3], kx3 = sp[rb + 4],
                kx4 = sp[rb + 5], kx5 = sp[rb + 6], kx6 = sp[rb + 7],
                kx7 = sp[rb + 8];

    const int t0 = tch * 512 + tg;
    const size_t base = (size_t)bb * TT * CC + (size_t)t0 * CC + c0 + ci;
    const float* px = x + base;
    float*       po = out + base;

    #pragma unroll 4
    for (int i = 0; i < 128; ++i) {
        const float xv = px[(size_t)i * 4 * CC];
        const float z  = fmaf(xv, a, bz);
        int idx = (z >= kx1) + (z >= kx2) + (z >= kx3) + (z >= kx4)
                + (z >= kx5) + (z >= kx6) + (z >= kx7);          // 0..7
        const int ib = rb + BINOFF + idx * 8;
        const float kxl  = sp[ib + 0];
        const float invw = sp[ib + 1];
        const float kyl  = sp[ib + 2];
        const float P    = sp[ib + 3];
        const float Q    = sp[ib + 4];
        const float R    = sp[ib + 5];
        const float S    = sp[ib + 6];
        float zeta = (z - kxl) * invw;
        zeta = fminf(fmaxf(zeta, 0.f), 1.f);
        const float u     = zeta * (1.f - zeta);
        const float numer = fmaf(P * zeta, zeta, Q * u);
        const float denom = fmaf(R, u, S);
        const float res   = fmaf(numer, __builtin_amdgcn_rcpf(fmaxf(denom, 1e-8f)), kyl);
        const float o = (z < -BOUNDF || z > BOUNDF) ? z : res;
        po[(size_t)i * 4 * CC] = o;
    }
}

extern "C" void kernel_launch(void* const* d_in, const int* in_sizes, int n_in,
                              void* d_out, int out_size, void* d_ws, size_t ws_size,
                              hipStream_t stream) {
    const float* x  = (const float*)d_in[0];
    const float* W1 = (const float*)d_in[1];
    const float* b1 = (const float*)d_in[2];
    const float* W2 = (const float*)d_in[3];
    const float* b2 = (const float*)d_in[4];
    float* out = (float*)d_out;
    float* ws  = (float*)d_ws;

    k_stats<<<dim3(8, NB), dim3(1024), 0, stream>>>(x, W1, b1, W2, b2, ws);
    k_apply<<<dim3(8, 8, NB), dim3(256), 0, stream>>>(x, ws, out);
}

// Round 2
// 163.231 us; speedup vs baseline: 1.0932x; 1.0932x over previous
//
#include <hip/hip_runtime.h>
#include <math.h>

#define KNOTS 8
#define HIDN 32
#define TT 4096
#define CC 512
#define NB 32
#define BOUNDF 5.0f

// ws layout per 64-channel tile (tile = bb*8 + ctile), all in floats:
//   [0..63]        a   (= 1/sigma)
//   [64..127]      b   (= -mu/sigma)
//   [128..575]     kx_j[j=1..7][64]
//   [576..2623]    binsA[8][64] float4 = (kx_l, 1/w, ky_l, h*s)
//   [2624..4671]   binsB[8][64] float4 = (h*d0, d1+d0-2s, s, 0)
#define HEADF 576
#define TILEF 4672

// ---------------- Kernel 1: per-row moments + MLP -> spline params ----------------
__global__ __launch_bounds__(1024, 4)
void k_stats(const float* __restrict__ x, const float* __restrict__ W1,
             const float* __restrict__ b1, const float* __restrict__ W2,
             const float* __restrict__ b2, float* __restrict__ ws)
{
    const int bb = blockIdx.y;          // batch 0..31
    const int ctile = blockIdx.x;       // 0..7
    const int c0 = ctile * 64;
    const int ci = threadIdx.x & 63;
    const int tg = threadIdx.x >> 6;    // 0..15

    const float* px = x + (size_t)bb * TT * CC + c0 + ci;
    float s1 = 0.f, s2 = 0.f, s3 = 0.f, s4 = 0.f;
    #pragma unroll 4
    for (int t = tg; t < TT; t += 16) {
        float v  = px[(size_t)t * CC];
        float v2 = v * v;
        s1 += v;
        s2 = fmaf(v,  v,  s2);
        s3 = fmaf(v2, v,  s3);
        s4 = fmaf(v2, v2, s4);
    }

    __shared__ float red[16][4][64];
    red[tg][0][ci] = s1; red[tg][1][ci] = s2; red[tg][2][ci] = s3; red[tg][3][ci] = s4;
    __syncthreads();

    __shared__ float mom[4][64];
    if (threadIdx.x < 256) {
        const int m = threadIdx.x >> 6, c = threadIdx.x & 63;
        float acc = 0.f;
        #pragma unroll
        for (int g = 0; g < 16; ++g) acc += red[g][m][c];
        mom[m][c] = acc;
    }
    __syncthreads();
    if (threadIdx.x >= 64) return;

    // ---- per-row finalize: one lane per row ----
    const float n  = (float)TT;
    const float t1 = mom[0][ci], t2 = mom[1][ci], t3 = mom[2][ci], t4 = mom[3][ci];
    const float mu  = t1 / n;
    const float ex2 = t2 / n, ex3 = t3 / n, ex4 = t4 / n;
    float var = (t2 - n * mu * mu) / (n - 1.f);
    var = fmaxf(var, 0.f);
    const float sig  = fmaxf(sqrtf(var), 1e-4f);
    const float inv  = 1.f / sig;
    const float mu2  = mu * mu;
    const float ez3  = ex3 - 3.f * mu * ex2 + 2.f * mu * mu2;
    const float ez4  = ex4 - 4.f * mu * ex3 + 6.f * mu2 * ex2 - 3.f * mu2 * mu2;
    const float inv2 = inv * inv;
    const float skew  = ez3 * inv2 * inv;
    const float ekurt = ez4 * inv2 * inv2 - 3.f;

    // MLP: hid = relu(stats @ W1^T + b1)
    float hid[HIDN];
    #pragma unroll
    for (int h = 0; h < HIDN; ++h) {
        float v = fmaf(W1[2*h], skew, fmaf(W1[2*h+1], ekurt, b1[h]));
        hid[h] = fmaxf(v, 0.f);
    }

    float e[KNOTS], kxr[KNOTS+1], kyr[KNOTS+1], dr[KNOTS+1];
    // raw[0..7] -> widths softmax -> kx knots
    {
        float mx = -1e30f;
        #pragma unroll
        for (int o = 0; o < KNOTS; ++o) {
            float acc = b2[o];
            #pragma unroll
            for (int h = 0; h < HIDN; ++h) acc = fmaf(W2[o*HIDN + h], hid[h], acc);
            e[o] = acc; mx = fmaxf(mx, acc);
        }
        float sum = 0.f;
        #pragma unroll
        for (int o = 0; o < KNOTS; ++o) { e[o] = expf(e[o] - mx); sum += e[o]; }
        const float scale = (2.f * BOUNDF) / sum;
        float cum = -BOUNDF; kxr[0] = -BOUNDF;
        #pragma unroll
        for (int o = 0; o < KNOTS; ++o) { cum = fmaf(e[o], scale, cum); kxr[o+1] = cum; }
    }
    // raw[8..15] -> heights softmax -> ky knots
    {
        float mx = -1e30f;
        #pragma unroll
        for (int o = 0; o < KNOTS; ++o) {
            float acc = b2[KNOTS + o];
            #pragma unroll
            for (int h = 0; h < HIDN; ++h) acc = fmaf(W2[(KNOTS+o)*HIDN + h], hid[h], acc);
            e[o] = acc; mx = fmaxf(mx, acc);
        }
        float sum = 0.f;
        #pragma unroll
        for (int o = 0; o < KNOTS; ++o) { e[o] = expf(e[o] - mx); sum += e[o]; }
        const float scale = (2.f * BOUNDF) / sum;
        float cum = -BOUNDF; kyr[0] = -BOUNDF;
        #pragma unroll
        for (int o = 0; o < KNOTS; ++o) { cum = fmaf(e[o], scale, cum); kyr[o+1] = cum; }
    }
    // raw[16..24] -> derivs = softplus + 1e-3
    #pragma unroll
    for (int o = 0; o < KNOTS+1; ++o) {
        float acc = b2[2*KNOTS + o];
        #pragma unroll
        for (int h = 0; h < HIDN; ++h) acc = fmaf(W2[(2*KNOTS+o)*HIDN + h], hid[h], acc);
        float sp = fmaxf(acc, 0.f) + log1pf(expf(-fabsf(acc)));
        dr[o] = sp + 1e-3f;
    }

    // ---- write param tile ----
    float* tb = ws + (size_t)(bb * 8 + ctile) * TILEF;
    tb[ci]      = inv;
    tb[64 + ci] = -mu * inv;
    #pragma unroll
    for (int j = 1; j <= 7; ++j) tb[128 + (j-1)*64 + ci] = kxr[j];

    float4* binsA = (float4*)(tb + HEADF);
    float4* binsB = binsA + KNOTS * 64;
    #pragma unroll
    for (int j = 0; j < KNOTS; ++j) {
        const float w  = kxr[j+1] - kxr[j];
        const float wm = fmaxf(w, 1e-8f);
        const float h  = kyr[j+1] - kyr[j];
        const float s  = h / wm;
        float4 A, Bq;
        A.x = kxr[j];            // kx_l
        A.y = 1.f / wm;          // 1/w
        A.z = kyr[j];            // ky_l
        A.w = h * s;             // P
        Bq.x = h * dr[j];        // Q
        Bq.y = dr[j+1] + dr[j] - 2.f * s;  // R
        Bq.z = s;                // S
        Bq.w = 0.f;
        binsA[j*64 + ci] = A;
        binsB[j*64 + ci] = Bq;
    }
}

// ---------------- Kernel 2: apply RQS spline elementwise ----------------
__global__ __launch_bounds__(256, 4)
void k_apply(const float* __restrict__ x, const float* __restrict__ ws,
             float* __restrict__ out)
{
    const int tch   = blockIdx.x;   // 0..7  (t chunk of 512)
    const int ctile = blockIdx.y;   // 0..7
    const int bb    = blockIdx.z;   // 0..31
    const int c0 = ctile * 64;
    const int ci = threadIdx.x & 63;
    const int tg = threadIdx.x >> 6;  // 0..3

    __shared__ float sp[TILEF];
    {
        const float4* src = (const float4*)(ws + (size_t)(bb * 8 + ctile) * TILEF);
        float4* dst = (float4*)sp;
        for (int i = threadIdx.x; i < TILEF / 4; i += 256) dst[i] = src[i];
    }
    __syncthreads();

    const float a  = sp[ci];
    const float bz = sp[64 + ci];
    const float kx1 = sp[128 + 0*64 + ci], kx2 = sp[128 + 1*64 + ci],
                kx3 = sp[128 + 2*64 + ci], kx4 = sp[128 + 3*64 + ci],
                kx5 = sp[128 + 4*64 + ci], kx6 = sp[128 + 5*64 + ci],
                kx7 = sp[128 + 6*64 + ci];
    const float4* binsA = (const float4*)(sp + HEADF);
    const float4* binsB = binsA + KNOTS * 64;

    const int t0 = tch * 512 + tg;
    const size_t base = (size_t)bb * TT * CC + (size_t)t0 * CC + c0 + ci;
    const float* px = x + base;
    float*       po = out + base;

    #pragma unroll 4
    for (int i = 0; i < 128; ++i) {
        const float xv = px[(size_t)i * 4 * CC];
        const float z  = fmaf(xv, a, bz);
        const int idx = (z >= kx1) + (z >= kx2) + (z >= kx3) + (z >= kx4)
                      + (z >= kx5) + (z >= kx6) + (z >= kx7);     // 0..7
        const float4 A  = binsA[idx * 64 + ci];
        const float4 Bq = binsB[idx * 64 + ci];
        float zeta = (z - A.x) * A.y;
        zeta = fminf(fmaxf(zeta, 0.f), 1.f);
        const float u     = zeta * (1.f - zeta);
        const float numer = fmaf(A.w * zeta, zeta, Bq.x * u);
        const float denom = fmaf(Bq.y, u, Bq.z);
        const float res   = fmaf(numer, __builtin_amdgcn_rcpf(fmaxf(denom, 1e-8f)), A.z);
        const float o = (z < -BOUNDF || z > BOUNDF) ? z : res;
        __builtin_nontemporal_store(o, &po[(size_t)i * 4 * CC]);
    }
}

extern "C" void kernel_launch(void* const* d_in, const int* in_sizes, int n_in,
                              void* d_out, int out_size, void* d_ws, size_t ws_size,
                              hipStream_t stream) {
    const float* x  = (const float*)d_in[0];
    const float* W1 = (const float*)d_in[1];
    const float* b1 = (const float*)d_in[2];
    const float* W2 = (const float*)d_in[3];
    const float* b2 = (const float*)d_in[4];
    float* out = (float*)d_out;
    float* ws  = (float*)d_ws;

    k_stats<<<dim3(8, NB), dim3(1024), 0, stream>>>(x, W1, b1, W2, b2, ws);
    k_apply<<<dim3(8, 8, NB), dim3(256), 0, stream>>>(x, ws, out);
}

// Round 3
// 130.579 us; speedup vs baseline: 1.3665x; 1.2501x over previous
//
#include <hip/hip_runtime.h>
#include <math.h>

#define KNOTS 8
#define HIDN 32
#define TT 4096
#define CC 512
#define NB 32
#define BOUNDF 5.0f
#define CT 32          // channels per block
#define NTG 16         // t-groups (threads striding over T)

// One block = one (batch, 32-channel) slice. Phase 1: moments over T.
// Finalize: 32 lanes compute MLP -> spline params into LDS.
// Phase 2: re-read the same 0.5 MB slice in REVERSE t order (L3-hot) and apply.
__global__ __launch_bounds__(512, 4)
void k_fused(const float* __restrict__ x, const float* __restrict__ W1,
             const float* __restrict__ b1, const float* __restrict__ W2,
             const float* __restrict__ b2, float* __restrict__ out)
{
    const int bb = blockIdx.y;               // 0..31
    const int c0 = blockIdx.x * CT;          // 0,32,...,480
    const int ci = threadIdx.x & (CT - 1);   // 0..31
    const int tg = threadIdx.x >> 5;         // 0..15

    __shared__ float red[NTG][4][CT];
    __shared__ float mom[4][CT];
    __shared__ float pA[CT], pB[CT];
    __shared__ float pKx[7][CT];
    __shared__ float4 binsA[KNOTS][CT];      // (kx_l, 1/w, ky_l, h*s)
    __shared__ float4 binsB[KNOTS][CT];      // (h*d0, d1+d0-2s, s, 0)

    const size_t base = (size_t)bb * TT * CC + c0 + ci;
    const float* pxt = x + base + (size_t)tg * CC;

    // ---- Phase 1: raw moments (each thread: 256 elements, stride 16 in t) ----
    float s1 = 0.f, s2 = 0.f, s3 = 0.f, s4 = 0.f;
    #pragma unroll 8
    for (int k = 0; k < TT / NTG; ++k) {
        float v  = pxt[(size_t)k * (NTG * CC)];
        float v2 = v * v;
        s1 += v;
        s2 = fmaf(v,  v,  s2);
        s3 = fmaf(v2, v,  s3);
        s4 = fmaf(v2, v2, s4);
    }
    red[tg][0][ci] = s1; red[tg][1][ci] = s2;
    red[tg][2][ci] = s3; red[tg][3][ci] = s4;
    __syncthreads();

    if (threadIdx.x < 4 * CT) {
        const int m = threadIdx.x >> 5, c = threadIdx.x & (CT - 1);
        float acc = 0.f;
        #pragma unroll
        for (int g = 0; g < NTG; ++g) acc += red[g][m][c];
        mom[m][c] = acc;
    }
    __syncthreads();

    // ---- Finalize: one lane per channel row ----
    if (threadIdx.x < CT) {
        const int c = threadIdx.x;
        const float n  = (float)TT;
        const float t1 = mom[0][c], t2 = mom[1][c], t3 = mom[2][c], t4 = mom[3][c];
        const float mu  = t1 / n;
        const float ex2 = t2 / n, ex3 = t3 / n, ex4 = t4 / n;
        float var = (t2 - n * mu * mu) / (n - 1.f);
        var = fmaxf(var, 0.f);
        const float sig  = fmaxf(sqrtf(var), 1e-4f);
        const float inv  = 1.f / sig;
        const float mu2  = mu * mu;
        const float ez3  = ex3 - 3.f * mu * ex2 + 2.f * mu * mu2;
        const float ez4  = ex4 - 4.f * mu * ex3 + 6.f * mu2 * ex2 - 3.f * mu2 * mu2;
        const float inv2 = inv * inv;
        const float skew  = ez3 * inv2 * inv;
        const float ekurt = ez4 * inv2 * inv2 - 3.f;

        float hid[HIDN];
        #pragma unroll
        for (int h = 0; h < HIDN; ++h) {
            float v = fmaf(W1[2*h], skew, fmaf(W1[2*h+1], ekurt, b1[h]));
            hid[h] = fmaxf(v, 0.f);
        }

        float e[KNOTS], kxr[KNOTS+1], kyr[KNOTS+1], dr[KNOTS+1];
        {   // widths -> kx
            float mx = -1e30f;
            #pragma unroll
            for (int o = 0; o < KNOTS; ++o) {
                float acc = b2[o];
                #pragma unroll
                for (int h = 0; h < HIDN; ++h) acc = fmaf(W2[o*HIDN + h], hid[h], acc);
                e[o] = acc; mx = fmaxf(mx, acc);
            }
            float sum = 0.f;
            #pragma unroll
            for (int o = 0; o < KNOTS; ++o) { e[o] = expf(e[o] - mx); sum += e[o]; }
            const float scale = (2.f * BOUNDF) / sum;
            float cum = -BOUNDF; kxr[0] = -BOUNDF;
            #pragma unroll
            for (int o = 0; o < KNOTS; ++o) { cum = fmaf(e[o], scale, cum); kxr[o+1] = cum; }
        }
        {   // heights -> ky
            float mx = -1e30f;
            #pragma unroll
            for (int o = 0; o < KNOTS; ++o) {
                float acc = b2[KNOTS + o];
                #pragma unroll
                for (int h = 0; h < HIDN; ++h) acc = fmaf(W2[(KNOTS+o)*HIDN + h], hid[h], acc);
                e[o] = acc; mx = fmaxf(mx, acc);
            }
            float sum = 0.f;
            #pragma unroll
            for (int o = 0; o < KNOTS; ++o) { e[o] = expf(e[o] - mx); sum += e[o]; }
            const float scale = (2.f * BOUNDF) / sum;
            float cum = -BOUNDF; kyr[0] = -BOUNDF;
            #pragma unroll
            for (int o = 0; o < KNOTS; ++o) { cum = fmaf(e[o], scale, cum); kyr[o+1] = cum; }
        }
        #pragma unroll
        for (int o = 0; o < KNOTS+1; ++o) {  // derivs = softplus + 1e-3
            float acc = b2[2*KNOTS + o];
            #pragma unroll
            for (int h = 0; h < HIDN; ++h) acc = fmaf(W2[(2*KNOTS+o)*HIDN + h], hid[h], acc);
            float sp = fmaxf(acc, 0.f) + log1pf(expf(-fabsf(acc)));
            dr[o] = sp + 1e-3f;
        }

        pA[c] = inv;
        pB[c] = -mu * inv;
        #pragma unroll
        for (int j = 1; j <= 7; ++j) pKx[j-1][c] = kxr[j];
        #pragma unroll
        for (int j = 0; j < KNOTS; ++j) {
            const float w  = kxr[j+1] - kxr[j];
            const float wm = fmaxf(w, 1e-8f);
            const float h  = kyr[j+1] - kyr[j];
            const float s  = h / wm;
            float4 A, Bq;
            A.x = kxr[j];  A.y = 1.f / wm;  A.z = kyr[j];  A.w = h * s;
            Bq.x = h * dr[j];  Bq.y = dr[j+1] + dr[j] - 2.f * s;  Bq.z = s;  Bq.w = 0.f;
            binsA[j][c] = A;
            binsB[j][c] = Bq;
        }
    }
    __syncthreads();

    // ---- Phase 2: re-read slice in REVERSE t order, apply spline ----
    const float a  = pA[ci];
    const float bz = pB[ci];
    const float kx1 = pKx[0][ci], kx2 = pKx[1][ci], kx3 = pKx[2][ci],
                kx4 = pKx[3][ci], kx5 = pKx[4][ci], kx6 = pKx[5][ci],
                kx7 = pKx[6][ci];
    float* pot = out + base + (size_t)tg * CC;

    for (int kb = TT / NTG / 8 - 1; kb >= 0; --kb) {   // 31..0 (reverse)
        float xv[8];
        #pragma unroll
        for (int j = 0; j < 8; ++j)
            xv[j] = pxt[(size_t)(kb * 8 + j) * (NTG * CC)];
        #pragma unroll
        for (int j = 0; j < 8; ++j) {
            const float z = fmaf(xv[j], a, bz);
            const int idx = (z >= kx1) + (z >= kx2) + (z >= kx3) + (z >= kx4)
                          + (z >= kx5) + (z >= kx6) + (z >= kx7);
            const float4 A  = binsA[idx][ci];
            const float4 Bq = binsB[idx][ci];
            float zeta = (z - A.x) * A.y;
            zeta = fminf(fmaxf(zeta, 0.f), 1.f);
            const float u     = zeta * (1.f - zeta);
            const float numer = fmaf(A.w * zeta, zeta, Bq.x * u);
            const float denom = fmaf(Bq.y, u, Bq.z);
            const float res   = fmaf(numer, __builtin_amdgcn_rcpf(fmaxf(denom, 1e-8f)), A.z);
            const float o = (z < -BOUNDF || z > BOUNDF) ? z : res;
            __builtin_nontemporal_store(o, &pot[(size_t)(kb * 8 + j) * (NTG * CC)]);
        }
    }
}

extern "C" void kernel_launch(void* const* d_in, const int* in_sizes, int n_in,
                              void* d_out, int out_size, void* d_ws, size_t ws_size,
                              hipStream_t stream) {
    const float* x  = (const float*)d_in[0];
    const float* W1 = (const float*)d_in[1];
    const float* b1 = (const float*)d_in[2];
    const float* W2 = (const float*)d_in[3];
    const float* b2 = (const float*)d_in[4];
    float* out = (float*)d_out;

    k_fused<<<dim3(CC / CT, NB), dim3(512), 0, stream>>>(x, W1, b1, W2, b2, out);
}